// Round 6
// baseline (551.122 us; speedup 1.0000x reference)
//
#include <hip/hip_runtime.h>
#include <hip/hip_bf16.h>
#include <stdint.h>

// Problem constants (fixed by reference setup_inputs)
#define T_ 800
#define B_ 16
#define D_ 256
#define V_ 4001
#define U_ 100
#define S_ 201      // 2U+1
#define SP 204      // S padded to multiple of 4 for float4 loads in alpha
#define M_ (T_*B_)  // 12800 GEMM rows
#define NEGF (-1e30f)
#define L2E 1.4426950408889634f
#define LN2 0.6931471805599453f

typedef __bf16 bf16;
typedef __bf16 bf16x8 __attribute__((ext_vector_type(8)));
typedef float f32x4 __attribute__((ext_vector_type(4)));

// Workspace layout (bytes). Total ~19.2 MB.
#define A_OFF     0          // bf16 A[12800][256]            6,553,600
#define WT_OFF    6553600    // bf16 Wt[4096][256] (padded)   2,097,152
#define EMIT_OFF  8650752    // f32 emit[B][T][SP] (log2 domain) 10,444,800
#define EXT_OFF   19095552   // i32 ext[16][204]                 13,056
#define AMASK_OFF 19108608   // f32 amask[16][204] (additive)    13,056
#define LENS_OFF  19121664   // i32 lens[16]

// ---------------- prep: ext labels, allow-mask (additive), label lens ----
__global__ void prep_kernel(const int* __restrict__ y, float* __restrict__ out,
                            int* __restrict__ ext, float* __restrict__ amask,
                            int* __restrict__ lens) {
  const int tid = threadIdx.x;
  if (tid == 0) out[0] = 0.f;  // loss accumulator (alpha atomicAdds later)
  if (tid < B_) {
    int cnt = 0;
    for (int u = 0; u < U_; u++) cnt += (y[u*B_ + tid] != 1) ? 1 : 0;
    lens[tid] = cnt;
  }
  for (int idx = tid; idx < B_*SP; idx += 256) {
    int b = idx / SP, s = idx - b*SP;
    int e = 0;
    if (s < S_ && (s & 1)) e = y[((s-1) >> 1)*B_ + b];
    ext[idx] = e;
    float am = NEGF;  // additive mask for the s-2 transition (log domain)
    if ((s & 1) && s >= 3 && s < S_) {
      int e2 = y[((s-3) >> 1)*B_ + b];
      if (e != 0 && e != e2) am = 0.f;
    }
    amask[idx] = am;
  }
}

// ---------------- cast ctx (f32) -> A (bf16), element-wise ---------------
__global__ void cast_a_kernel(const float* __restrict__ ctx, bf16* __restrict__ A) {
  int i = blockIdx.x * blockDim.x + threadIdx.x;  // exactly 819200 threads
  float4 v = ((const float4*)ctx)[i];
  union { bf16 h[4]; uint2 u; } p;
  p.h[0] = (bf16)v.x; p.h[1] = (bf16)v.y; p.h[2] = (bf16)v.z; p.h[3] = (bf16)v.w;
  ((uint2*)A)[i] = p.u;
}

// ---------------- transpose W [256][4001] f32 -> Wt [4096][256] bf16 -----
__global__ void trans_w_kernel(const float* __restrict__ W, bf16* __restrict__ Wt) {
  __shared__ float tile[32][33];
  const int c = threadIdx.x & 31, r = threadIdx.x >> 5;  // 32x8 threads
  const int n0 = blockIdx.x * 32, k0 = blockIdx.y * 32;
  for (int rr = r; rr < 32; rr += 8) {
    int n = n0 + c;
    tile[rr][c] = (n < V_) ? W[(size_t)(k0+rr)*V_ + n] : 0.f;
  }
  __syncthreads();
  for (int rr = r; rr < 32; rr += 8) {
    Wt[(size_t)(n0+rr)*D_ + k0 + c] = (bf16)tile[c][rr];
  }
}

// ---------------- GEMM: logits = A x Wt^T + bias -> out[1..] (f32) -------
// 128x128 tile, BK=64, mfma_f32_16x16x32_bf16, wave tile 64x64 (4x4 C-tiles)
// LDS row stride 72 bf16 (144 B = 9*16 B) -> bank-uniform b128 reads.
// R6: XCD-aware block swizzle (bijective, nwg=3200, 3200%8==0): each XCD
// gets a contiguous run of m-rows -> A-tile + Wt panel reuse in its L2
// instead of 8x cross-XCD HBM re-fetch.
__global__ __launch_bounds__(256) void gemm_kernel(
    const bf16* __restrict__ A, const bf16* __restrict__ Wt,
    const float* __restrict__ bias, float* __restrict__ out) {
  __shared__ bf16 smA[128*72];
  __shared__ bf16 smB[128*72];
  const int tid = threadIdx.x;
  const int l = tid & 63, w = tid >> 6;
  const int wr = w >> 1, wc = w & 1;
  const int orig = blockIdx.y * 32 + blockIdx.x;       // 0..3199
  const int virt = (orig & 7) * 400 + (orig >> 3);     // XCD-chunked remap
  const int n0 = (virt & 31) * 128, m0 = (virt >> 5) * 128;

  f32x4 acc[4][4];
#pragma unroll
  for (int i = 0; i < 4; i++)
#pragma unroll
    for (int j = 0; j < 4; j++) acc[i][j] = (f32x4){0.f, 0.f, 0.f, 0.f};

  for (int kt = 0; kt < 4; kt++) {
#pragma unroll
    for (int r = 0; r < 4; r++) {
      int j = (w*4 + r)*64 + l;        // 0..1023 16B-chunk slot
      int row = j >> 3, c = j & 7;     // row 0..127, chunk 0..7 (8 bf16)
      bf16x8 va = *(const bf16x8*)(A  + (size_t)(m0+row)*D_ + kt*64 + c*8);
      bf16x8 vb = *(const bf16x8*)(Wt + (size_t)(n0+row)*D_ + kt*64 + c*8);
      *(bf16x8*)((char*)smA + row*144 + (c<<4)) = va;
      *(bf16x8*)((char*)smB + row*144 + (c<<4)) = vb;
    }
    __syncthreads();
#pragma unroll
    for (int ks = 0; ks < 2; ks++) {
      bf16x8 af[4], bfr[4];
      const int cidx = ks*4 + (l >> 4);
#pragma unroll
      for (int t = 0; t < 4; t++) {
        int arow = wr*64 + t*16 + (l & 15);
        af[t]  = *(const bf16x8*)((const char*)smA + arow*144 + (cidx<<4));
        int brow = wc*64 + t*16 + (l & 15);
        bfr[t] = *(const bf16x8*)((const char*)smB + brow*144 + (cidx<<4));
      }
#pragma unroll
      for (int i = 0; i < 4; i++)
#pragma unroll
        for (int j = 0; j < 4; j++)
          acc[i][j] = __builtin_amdgcn_mfma_f32_16x16x32_bf16(af[i], bfr[j], acc[i][j], 0, 0, 0);
    }
    __syncthreads();
  }
  // epilogue: C layout col=lane&15, row=(lane>>4)*4+reg (verified m89/m91)
#pragma unroll
  for (int j = 0; j < 4; j++) {
    int gn = n0 + wc*64 + j*16 + (l & 15);
    if (gn < V_) {
      float bv = bias[gn];
#pragma unroll
      for (int i = 0; i < 4; i++) {
        int rbase = m0 + wr*64 + i*16 + ((l >> 4) << 2);
#pragma unroll
        for (int rg = 0; rg < 4; rg++) {
          out[1 + (size_t)(rbase + rg)*V_ + gn] = acc[i][j][rg] + bv;
        }
      }
    }
  }
}

// ---------------- per-row log_softmax in place + emit gather -------------
// emit stored TRANSPOSED [b][t][SP], log2 domain (pre-scaled by log2(e)).
__global__ __launch_bounds__(256) void softmax_gather_kernel(
    float* __restrict__ out, const int* __restrict__ ext, float* __restrict__ emit) {
  __shared__ float srow[4096];
  __shared__ float red[8];
  const int row = blockIdx.x, tid = threadIdx.x;
  float* rp = out + 1 + (size_t)row * V_;
  float v[16];
  float mx = NEGF;
#pragma unroll
  for (int j = 0; j < 16; j++) {
    int c = tid + j*256;
    v[j] = (c < V_) ? rp[c] : NEGF;
    mx = fmaxf(mx, v[j]);
  }
#pragma unroll
  for (int o = 32; o > 0; o >>= 1) mx = fmaxf(mx, __shfl_xor(mx, o));
  if ((tid & 63) == 0) red[tid >> 6] = mx;
  __syncthreads();
  mx = fmaxf(fmaxf(red[0], red[1]), fmaxf(red[2], red[3]));
  float sm = 0.f;
#pragma unroll
  for (int j = 0; j < 16; j++) sm += __builtin_amdgcn_exp2f((v[j] - mx) * L2E);
#pragma unroll
  for (int o = 32; o > 0; o >>= 1) sm += __shfl_xor(sm, o);
  if ((tid & 63) == 0) red[4 + (tid >> 6)] = sm;
  __syncthreads();
  const float lse = mx + __builtin_amdgcn_logf(red[4] + red[5] + red[6] + red[7]) * LN2;
#pragma unroll
  for (int j = 0; j < 16; j++) {
    int c = tid + j*256;
    if (c < V_) {
      float lp = v[j] - lse;
      rp[c] = lp;        // final logps output
      srow[c] = lp;      // for the emit gather below
    }
  }
  __syncthreads();
  // emit in log2 domain: alpha runs in log2, avoids mul-by-L2E per step
  if (tid < SP) {
    float e = NEGF;
    if (tid < S_) e = srow[ext[(row & (B_-1))*SP + tid]] * L2E;
    emit[((size_t)(row & (B_-1))*T_ + (row >> 4))*SP + tid] = e;
  }
}

// ---------------- CTC alpha recursion (log2 domain) ----------------------
// R6: R5 showed alpha's 390 cyc/step is NOT memory (ring+lookahead both
// neutral) -- it's ALU/trans dependency latency fully exposed at 1 wave/CU.
// Fix: co-residency. 2 blocks x 512 threads; wave w = batch 8*bid+w; 8
// waves/CU = 2 waves/SIMD, so each wave's stalls are filled by its
// SIMD-mate (issue-bound ~150 cyc/step instead of 390). Also:
//   - even states (4l, 4l+2) are always blanks -> lae2 (no s-2 term), and
//     the second DPP (sh2) becomes statically dead -> 1 DPP/step.
//   - LDS ring/producers deleted (proven neutral); direct global loads
//     with 2-deep register lookahead, hidden by the co-wave.
// Idle lanes 51..63 compute garbage but it never propagates down (DPP shr
// moves data up-lane only) and aS reads stop at state 200.
__device__ __forceinline__ float dpp_shr1(float x) {
  // lane l gets lane l-1's x; lane 0 gets 'old' = NEGF (bound_ctrl=0 keeps old)
  int r = __builtin_amdgcn_update_dpp(__float_as_int(NEGF), __float_as_int(x),
                                      0x138 /*wave_shr:1*/, 0xf, 0xf, false);
  return __int_as_float(r);
}

__device__ __forceinline__ float lae3(float a, float b, float c) {
  float m  = fmaxf(fmaxf(a, b), c);                 // v_max3_f32
  float md = __builtin_amdgcn_fmed3f(a, b, c);      // v_med3_f32
  float mn = fminf(fminf(a, b), c);                 // v_min3_f32
  float s = 1.0f + __builtin_amdgcn_exp2f(md - m) + __builtin_amdgcn_exp2f(mn - m);
  return m + __builtin_amdgcn_logf(s);              // v_log_f32 (log2)
}

__device__ __forceinline__ float lae2(float a, float b) {
  float m  = fmaxf(a, b);
  float mn = fminf(a, b);
  float s = 1.0f + __builtin_amdgcn_exp2f(mn - m);
  return m + __builtin_amdgcn_logf(s);
}

__global__ __launch_bounds__(512) void alpha_kernel(
    const float* __restrict__ emit, const float* __restrict__ amp,
    const int* __restrict__ lens, float* __restrict__ out) {
  __shared__ float aS[8][256];
  const int wv = threadIdx.x >> 6, l = threadIdx.x & 63;
  const int b = blockIdx.x * 8 + wv;   // one wave per batch
  const bool act = (l < 51);           // 51*4 = 204 = SP
  const float* ebase = emit + (size_t)b*T_*SP;
  const float4 NEG4 = make_float4(NEGF, NEGF, NEGF, NEGF);

  float4 am = act ? *(const float4*)(amp + b*SP + 4*l) : NEG4;
  float a0 = NEGF, a1 = NEGF, a2 = NEGF, a3 = NEGF;
  if (l == 0) { a0 = ebase[0]; a1 = ebase[1]; }  // alpha0: only s=0,1

  auto ld = [&](int t) -> float4 {
    return *(const float4*)(ebase + (size_t)t*SP + 4*l);
  };
  auto step = [&](float4 cur) {
    float sh1 = dpp_shr1(a3);  // alpha[s-1] for state 4l (= prev lane's 4l+3)
    // states 4l, 4l+2 are even = blank: s-2 transition statically forbidden
    float n0 = lae2(a0, sh1)              + cur.x;
    float n1 = lae3(a1, a0, sh1 + am.y)   + cur.y;
    float n2 = lae2(a2, a1)               + cur.z;
    float n3 = lae3(a3, a2, a1  + am.w)   + cur.w;
    a0 = n0; a1 = n1; a2 = n2; a3 = n3;
  };

  // 799 steps (t = 1..799), 2-deep register lookahead
  float4 c0 = ld(1), c1 = ld(2);
  for (int k = 0; k < 398; k++) {       // steps t = 1..796
    float4 p0 = c0; c0 = ld(2*k + 3);
    step(p0);
    float4 p1 = c1; c1 = ld(2*k + 4);
    step(p1);
  }
  step(c0);       // t = 797
  step(c1);       // t = 798
  step(ld(799));  // t = 799

  // same-wave LDS roundtrip (no barrier needed: writer == reader wave)
  aS[wv][4*l+0] = a0; aS[wv][4*l+1] = a1;
  aS[wv][4*l+2] = a2; aS[wv][4*l+3] = a3;
  if (l == 0) {
    int e = 2 * lens[b];
    float la = aS[wv][e], lb = aS[wv][e-1];
    float m = fmaxf(la, lb);
    float ll2 = m + log2f(exp2f(la - m) + exp2f(lb - m));
    atomicAdd(out, -ll2 * LN2);  // loss = -sum_b ll
  }
}

// ---------------- launch ----------------
extern "C" void kernel_launch(void* const* d_in, const int* in_sizes, int n_in,
                              void* d_out, int out_size, void* d_ws, size_t ws_size,
                              hipStream_t stream) {
  const float* ctx  = (const float*)d_in[0];  // [800,16,256]
  const int*   y    = (const int*)  d_in[1];  // [100,16]
  const float* W    = (const float*)d_in[2];  // [256,4001]
  const float* bias = (const float*)d_in[3];  // [4001]
  float* out = (float*)d_out;                 // [1 + 800*16*4001]
  char* ws = (char*)d_ws;
  bf16*  A     = (bf16*) (ws + A_OFF);
  bf16*  Wt    = (bf16*) (ws + WT_OFF);
  float* emit  = (float*)(ws + EMIT_OFF);
  int*   ext   = (int*)  (ws + EXT_OFF);
  float* amp   = (float*)(ws + AMASK_OFF);
  int*   lens  = (int*)  (ws + LENS_OFF);

  hipLaunchKernelGGL(prep_kernel, dim3(1), dim3(256), 0, stream, y, out, ext, amp, lens);
  hipLaunchKernelGGL(cast_a_kernel, dim3(3200), dim3(256), 0, stream, ctx, A);
  hipLaunchKernelGGL(trans_w_kernel, dim3(128, 8), dim3(256), 0, stream, W, Wt);
  hipLaunchKernelGGL(gemm_kernel, dim3(32, 100), dim3(256), 0, stream, A, Wt, bias, out);
  hipLaunchKernelGGL(softmax_gather_kernel, dim3(12800), dim3(256), 0, stream, out, ext, emit);
  hipLaunchKernelGGL(alpha_kernel, dim3(2), dim3(512), 0, stream, emit, amp, lens, out);
}

// Round 7
// 454.984 us; speedup vs baseline: 1.2113x; 1.2113x over previous
//
#include <hip/hip_runtime.h>
#include <hip/hip_bf16.h>
#include <stdint.h>

// Problem constants (fixed by reference setup_inputs)
#define T_ 800
#define B_ 16
#define D_ 256
#define V_ 4001
#define U_ 100
#define S_ 201      // 2U+1
#define SP 204      // S padded to multiple of 4 for float4 loads in alpha
#define M_ (T_*B_)  // 12800 GEMM rows
#define NEGF (-1e30f)
#define L2E 1.4426950408889634f
#define LN2 0.6931471805599453f

typedef __bf16 bf16;
typedef __bf16 bf16x8 __attribute__((ext_vector_type(8)));
typedef float f32x4 __attribute__((ext_vector_type(4)));

// Workspace layout (bytes). Total ~19.2 MB.
#define A_OFF     0          // bf16 A[12800][256]            6,553,600
#define WT_OFF    6553600    // bf16 Wt[4096][256] (padded)   2,097,152
#define EMIT_OFF  8650752    // f32 emit[B][T][SP] (log2 domain) 10,444,800
#define EXT_OFF   19095552   // i32 ext[16][204]                 13,056
#define AMASK_OFF 19108608   // f32 amask[16][204] (additive)    13,056
#define LENS_OFF  19121664   // i32 lens[16]

// ---------------- prep: ext labels, allow-mask (additive), label lens ----
__global__ void prep_kernel(const int* __restrict__ y, float* __restrict__ out,
                            int* __restrict__ ext, float* __restrict__ amask,
                            int* __restrict__ lens) {
  const int tid = threadIdx.x;
  if (tid == 0) out[0] = 0.f;  // loss accumulator (alpha atomicAdds later)
  if (tid < B_) {
    int cnt = 0;
    for (int u = 0; u < U_; u++) cnt += (y[u*B_ + tid] != 1) ? 1 : 0;
    lens[tid] = cnt;
  }
  for (int idx = tid; idx < B_*SP; idx += 256) {
    int b = idx / SP, s = idx - b*SP;
    int e = 0;
    if (s < S_ && (s & 1)) e = y[((s-1) >> 1)*B_ + b];
    ext[idx] = e;
    float am = NEGF;  // additive mask for the s-2 transition (log domain)
    if ((s & 1) && s >= 3 && s < S_) {
      int e2 = y[((s-3) >> 1)*B_ + b];
      if (e != 0 && e != e2) am = 0.f;
    }
    amask[idx] = am;
  }
}

// ---------------- cast ctx (f32) -> A (bf16), element-wise ---------------
__global__ void cast_a_kernel(const float* __restrict__ ctx, bf16* __restrict__ A) {
  int i = blockIdx.x * blockDim.x + threadIdx.x;  // exactly 819200 threads
  float4 v = ((const float4*)ctx)[i];
  union { bf16 h[4]; uint2 u; } p;
  p.h[0] = (bf16)v.x; p.h[1] = (bf16)v.y; p.h[2] = (bf16)v.z; p.h[3] = (bf16)v.w;
  ((uint2*)A)[i] = p.u;
}

// ---------------- transpose W [256][4001] f32 -> Wt [4096][256] bf16 -----
__global__ void trans_w_kernel(const float* __restrict__ W, bf16* __restrict__ Wt) {
  __shared__ float tile[32][33];
  const int c = threadIdx.x & 31, r = threadIdx.x >> 5;  // 32x8 threads
  const int n0 = blockIdx.x * 32, k0 = blockIdx.y * 32;
  for (int rr = r; rr < 32; rr += 8) {
    int n = n0 + c;
    tile[rr][c] = (n < V_) ? W[(size_t)(k0+rr)*V_ + n] : 0.f;
  }
  __syncthreads();
  for (int rr = r; rr < 32; rr += 8) {
    Wt[(size_t)(n0+rr)*D_ + k0 + c] = (bf16)tile[c][rr];
  }
}

// ---------------- GEMM: logits = A x Wt^T + bias -> out[1..] (f32) -------
// 128x128 tile, BK=64, mfma_f32_16x16x32_bf16, wave tile 64x64 (4x4 C-tiles)
// LDS row stride 72 bf16 (144 B = 9*16 B) -> bank-uniform b128 reads.
// XCD-aware block swizzle (bijective, 3200%8==0) for L2-local panel reuse.
__global__ __launch_bounds__(256) void gemm_kernel(
    const bf16* __restrict__ A, const bf16* __restrict__ Wt,
    const float* __restrict__ bias, float* __restrict__ out) {
  __shared__ bf16 smA[128*72];
  __shared__ bf16 smB[128*72];
  const int tid = threadIdx.x;
  const int l = tid & 63, w = tid >> 6;
  const int wr = w >> 1, wc = w & 1;
  const int orig = blockIdx.y * 32 + blockIdx.x;       // 0..3199
  const int virt = (orig & 7) * 400 + (orig >> 3);     // XCD-chunked remap
  const int n0 = (virt & 31) * 128, m0 = (virt >> 5) * 128;

  f32x4 acc[4][4];
#pragma unroll
  for (int i = 0; i < 4; i++)
#pragma unroll
    for (int j = 0; j < 4; j++) acc[i][j] = (f32x4){0.f, 0.f, 0.f, 0.f};

  for (int kt = 0; kt < 4; kt++) {
#pragma unroll
    for (int r = 0; r < 4; r++) {
      int j = (w*4 + r)*64 + l;        // 0..1023 16B-chunk slot
      int row = j >> 3, c = j & 7;     // row 0..127, chunk 0..7 (8 bf16)
      bf16x8 va = *(const bf16x8*)(A  + (size_t)(m0+row)*D_ + kt*64 + c*8);
      bf16x8 vb = *(const bf16x8*)(Wt + (size_t)(n0+row)*D_ + kt*64 + c*8);
      *(bf16x8*)((char*)smA + row*144 + (c<<4)) = va;
      *(bf16x8*)((char*)smB + row*144 + (c<<4)) = vb;
    }
    __syncthreads();
#pragma unroll
    for (int ks = 0; ks < 2; ks++) {
      bf16x8 af[4], bfr[4];
      const int cidx = ks*4 + (l >> 4);
#pragma unroll
      for (int t = 0; t < 4; t++) {
        int arow = wr*64 + t*16 + (l & 15);
        af[t]  = *(const bf16x8*)((const char*)smA + arow*144 + (cidx<<4));
        int brow = wc*64 + t*16 + (l & 15);
        bfr[t] = *(const bf16x8*)((const char*)smB + brow*144 + (cidx<<4));
      }
#pragma unroll
      for (int i = 0; i < 4; i++)
#pragma unroll
        for (int j = 0; j < 4; j++)
          acc[i][j] = __builtin_amdgcn_mfma_f32_16x16x32_bf16(af[i], bfr[j], acc[i][j], 0, 0, 0);
    }
    __syncthreads();
  }
  // epilogue: C layout col=lane&15, row=(lane>>4)*4+reg (verified m89/m91)
#pragma unroll
  for (int j = 0; j < 4; j++) {
    int gn = n0 + wc*64 + j*16 + (l & 15);
    if (gn < V_) {
      float bv = bias[gn];
#pragma unroll
      for (int i = 0; i < 4; i++) {
        int rbase = m0 + wr*64 + i*16 + ((l >> 4) << 2);
#pragma unroll
        for (int rg = 0; rg < 4; rg++) {
          out[1 + (size_t)(rbase + rg)*V_ + gn] = acc[i][j][rg] + bv;
        }
      }
    }
  }
}

// ---------------- per-row log_softmax in place + emit gather -------------
// emit stored TRANSPOSED [b][t][SP], log2 domain (pre-scaled by log2(e)).
__global__ __launch_bounds__(256) void softmax_gather_kernel(
    float* __restrict__ out, const int* __restrict__ ext, float* __restrict__ emit) {
  __shared__ float srow[4096];
  __shared__ float red[8];
  const int row = blockIdx.x, tid = threadIdx.x;
  float* rp = out + 1 + (size_t)row * V_;
  float v[16];
  float mx = NEGF;
#pragma unroll
  for (int j = 0; j < 16; j++) {
    int c = tid + j*256;
    v[j] = (c < V_) ? rp[c] : NEGF;
    mx = fmaxf(mx, v[j]);
  }
#pragma unroll
  for (int o = 32; o > 0; o >>= 1) mx = fmaxf(mx, __shfl_xor(mx, o));
  if ((tid & 63) == 0) red[tid >> 6] = mx;
  __syncthreads();
  mx = fmaxf(fmaxf(red[0], red[1]), fmaxf(red[2], red[3]));
  float sm = 0.f;
#pragma unroll
  for (int j = 0; j < 16; j++) sm += __builtin_amdgcn_exp2f((v[j] - mx) * L2E);
#pragma unroll
  for (int o = 32; o > 0; o >>= 1) sm += __shfl_xor(sm, o);
  if ((tid & 63) == 0) red[4 + (tid >> 6)] = sm;
  __syncthreads();
  const float lse = mx + __builtin_amdgcn_logf(red[4] + red[5] + red[6] + red[7]) * LN2;
#pragma unroll
  for (int j = 0; j < 16; j++) {
    int c = tid + j*256;
    if (c < V_) {
      float lp = v[j] - lse;
      rp[c] = lp;        // final logps output
      srow[c] = lp;      // for the emit gather below
    }
  }
  __syncthreads();
  // emit in log2 domain: alpha runs in log2, avoids mul-by-L2E per step
  if (tid < SP) {
    float e = NEGF;
    if (tid < S_) e = srow[ext[(row & (B_-1))*SP + tid]] * L2E;
    emit[((size_t)(row & (B_-1))*T_ + (row >> 4))*SP + tid] = e;
  }
}

// ---------------- CTC alpha recursion (lazy-logsumexp pairs) -------------
// R7: R2-R6 established the wall time = ONE wave's serial per-step chain;
// at 390 cyc/step it is the two DEPENDENT transcendentals (exp2 -> log2)
// per lae. Fix: represent alpha[s] = m[s] + log2(r[s]) as a PAIR and never
// materialize the log in the loop:
//   p  = max3(m_i)               <- m-recurrence: max+add ONLY (~20 cyc)
//   r' = sum r_i * exp2(m_i - p) <- exp2 inputs are PREVIOUS-step m's:
//                                   they issue a full step early, off-chain
//   m' = p + emit
// Exact (pure factoring of lae); all exp2 args <= 0 (p is the max) so no
// overflow; unreachable states stay pinned at m=-1e30 (exp2(-huge)=0).
// r in [1, 2*3^8] per 8 steps; per-iteration exponent-fold (exact bit ops)
// keeps it bounded; dynamic range lives in m -> no R3/R4 range wall.
// Feed: 8-deep register pipeline; sched_barrier(0) after each issue pins
// the loads (R1/R6: compiler otherwise sinks them to uses; VGPR=20 proof).
__device__ __forceinline__ float dpp_shr1f(float x, float oldv) {
  // lane l gets lane l-1's x; lane 0 keeps 'oldv' (bound_ctrl=0)
  int r = __builtin_amdgcn_update_dpp(__float_as_int(oldv), __float_as_int(x),
                                      0x138 /*wave_shr:1*/, 0xf, 0xf, false);
  return __int_as_float(r);
}
#define EX2 __builtin_amdgcn_exp2f

__global__ __launch_bounds__(64) void alpha_kernel(
    const float* __restrict__ emit, const float* __restrict__ amp,
    const int* __restrict__ lens, float* __restrict__ out) {
  __shared__ float aSm[256];
  __shared__ float aSr[256];
  const int b = blockIdx.x, l = threadIdx.x;
  const bool act = (l < 51);  // 51*4 = 204 = SP
  const float* ebase = emit + (size_t)b*T_*SP;
  const float4 NEG4 = make_float4(NEGF, NEGF, NEGF, NEGF);

  float4 am = act ? *(const float4*)(amp + b*SP + 4*l) : NEG4;
  float m0 = NEGF, m1 = NEGF, m2 = NEGF, m3 = NEGF;
  float r0 = 1.f, r1 = 1.f, r2 = 1.f, r3 = 1.f;
  if (l == 0) { m0 = ebase[0]; m1 = ebase[1]; }  // alpha0: only s=0,1

  auto ld = [&](int t) -> float4 {
    return *(const float4*)(ebase + (size_t)t*SP + 4*l);
  };

  auto step = [&](float4 cur) {
    float shm = dpp_shr1f(m3, NEGF);  // state 4l-1 (prev lane's 4l+3)
    float shr = dpp_shr1f(r3, 1.f);
    float sy = shm + am.y;            // s-2 source for state 4l+1, masked
    float aw = m1 + am.w;             // s-2 source for state 4l+3, masked
    float p0 = fmaxf(m0, shm);                    // even: no s-2
    float p1 = fmaxf(fmaxf(m1, m0), sy);
    float p2 = fmaxf(m2, m1);                     // even: no s-2
    float p3 = fmaxf(fmaxf(m3, m2), aw);
    float e00 = EX2(m0 - p0), e01 = EX2(shm - p0);
    float e10 = EX2(m1 - p1), e11 = EX2(m0 - p1), e12 = EX2(sy - p1);
    float e20 = EX2(m2 - p2), e21 = EX2(m1 - p2);
    float e30 = EX2(m3 - p3), e31 = EX2(m2 - p3), e32 = EX2(aw - p3);
    float n0 = fmaf(r0, e00, shr * e01);
    float n1 = fmaf(r1, e10, fmaf(r0, e11, shr * e12));
    float n2 = fmaf(r2, e20, r1 * e21);
    float n3 = fmaf(r3, e30, fmaf(r2, e31, r1 * e32));
    m0 = p0 + cur.x; m1 = p1 + cur.y; m2 = p2 + cur.z; m3 = p3 + cur.w;
    r0 = n0; r1 = n1; r2 = n2; r3 = n3;
  };

  auto fold1 = [&](float& m, float& r) {
    // exact: r = mant in [1,2), m += exponent (r always >= 1 pre-fold)
    uint32_t bits = __float_as_uint(r);
    int er = (int)(bits >> 23) - 127;
    r = __uint_as_float((bits & 0x007FFFFFu) | 0x3F800000u);
    m = m + (float)er;
  };

  // 8-deep pinned register pipeline over t = 1..799
  float4 buf[8];
#pragma unroll
  for (int j = 0; j < 8; j++) buf[j] = ld(1 + j);

  for (int it = 0; it < 99; ++it) {   // 99 x 8 = 792 steps: t = 1..792
#pragma unroll
    for (int j = 0; j < 8; j++) {
      float4 cur = buf[j];
      int tn = it*8 + j + 9;          // t + 8
      if (tn > 799) tn = 799;         // tail clamp (dup load, unused slot)
      buf[j] = ld(tn);
      __builtin_amdgcn_sched_barrier(0);  // pin: load cannot sink below
      step(cur);
    }
    fold1(m0, r0); fold1(m1, r1); fold1(m2, r2); fold1(m3, r3);
  }
  // drain: t = 793..799 live in buf[0..6]
#pragma unroll
  for (int j = 0; j < 7; j++) step(buf[j]);

  aSm[4*l+0] = m0; aSm[4*l+1] = m1; aSm[4*l+2] = m2; aSm[4*l+3] = m3;
  aSr[4*l+0] = r0; aSr[4*l+1] = r1; aSr[4*l+2] = r2; aSr[4*l+3] = r3;
  __syncthreads();
  if (l == 0) {
    int e = 2 * lens[b];
    float la = aSm[e]   + __builtin_amdgcn_logf(aSr[e]);
    float lb = aSm[e-1] + __builtin_amdgcn_logf(aSr[e-1]);
    float mm = fmaxf(la, lb);
    float ll2 = mm + log2f(exp2f(la - mm) + exp2f(lb - mm));
    atomicAdd(out, -ll2 * LN2);  // loss = -sum_b ll
  }
}

// ---------------- launch ----------------
extern "C" void kernel_launch(void* const* d_in, const int* in_sizes, int n_in,
                              void* d_out, int out_size, void* d_ws, size_t ws_size,
                              hipStream_t stream) {
  const float* ctx  = (const float*)d_in[0];  // [800,16,256]
  const int*   y    = (const int*)  d_in[1];  // [100,16]
  const float* W    = (const float*)d_in[2];  // [256,4001]
  const float* bias = (const float*)d_in[3];  // [4001]
  float* out = (float*)d_out;                 // [1 + 800*16*4001]
  char* ws = (char*)d_ws;
  bf16*  A     = (bf16*) (ws + A_OFF);
  bf16*  Wt    = (bf16*) (ws + WT_OFF);
  float* emit  = (float*)(ws + EMIT_OFF);
  int*   ext   = (int*)  (ws + EXT_OFF);
  float* amp   = (float*)(ws + AMASK_OFF);
  int*   lens  = (int*)  (ws + LENS_OFF);

  hipLaunchKernelGGL(prep_kernel, dim3(1), dim3(256), 0, stream, y, out, ext, amp, lens);
  hipLaunchKernelGGL(cast_a_kernel, dim3(3200), dim3(256), 0, stream, ctx, A);
  hipLaunchKernelGGL(trans_w_kernel, dim3(128, 8), dim3(256), 0, stream, W, Wt);
  hipLaunchKernelGGL(gemm_kernel, dim3(32, 100), dim3(256), 0, stream, A, Wt, bias, out);
  hipLaunchKernelGGL(softmax_gather_kernel, dim3(12800), dim3(256), 0, stream, out, ext, emit);
  hipLaunchKernelGGL(alpha_kernel, dim3(16), dim3(64), 0, stream, emit, amp, lens, out);
}

// Round 8
// 428.079 us; speedup vs baseline: 1.2874x; 1.0629x over previous
//
#include <hip/hip_runtime.h>
#include <hip/hip_bf16.h>
#include <stdint.h>

// Problem constants (fixed by reference setup_inputs)
#define T_ 800
#define B_ 16
#define D_ 256
#define V_ 4001
#define U_ 100
#define S_ 201      // 2U+1
#define SP 204      // S padded to multiple of 4 for float4 loads in alpha
#define M_ (T_*B_)  // 12800 GEMM rows
#define NEGF (-1e30f)
#define L2E 1.4426950408889634f
#define LN2 0.6931471805599453f

typedef __bf16 bf16;
typedef __bf16 bf16x8 __attribute__((ext_vector_type(8)));
typedef float f32x4 __attribute__((ext_vector_type(4)));

// Workspace layout (bytes). Total ~19.2 MB.
#define A_OFF     0          // bf16 A[12800][256]            6,553,600
#define WT_OFF    6553600    // bf16 Wt[4096][256] (padded)   2,097,152
#define EMIT_OFF  8650752    // f32 emit[B][T][SP] (log2 domain) 10,444,800
#define EXT_OFF   19095552   // i32 ext[16][204]                 13,056
#define AMASK_OFF 19108608   // f32 amask[16][204] (additive)    13,056
#define LENS_OFF  19121664   // i32 lens[16]

// ---------------- prep: ext labels, allow-mask (additive), label lens ----
__global__ void prep_kernel(const int* __restrict__ y, float* __restrict__ out,
                            int* __restrict__ ext, float* __restrict__ amask,
                            int* __restrict__ lens) {
  const int tid = threadIdx.x;
  if (tid == 0) out[0] = 0.f;  // loss accumulator (alpha atomicAdds later)
  if (tid < B_) {
    int cnt = 0;
    for (int u = 0; u < U_; u++) cnt += (y[u*B_ + tid] != 1) ? 1 : 0;
    lens[tid] = cnt;
  }
  for (int idx = tid; idx < B_*SP; idx += 256) {
    int b = idx / SP, s = idx - b*SP;
    int e = 0;
    if (s < S_ && (s & 1)) e = y[((s-1) >> 1)*B_ + b];
    ext[idx] = e;
    float am = NEGF;  // additive mask for the s-2 transition (log domain)
    if ((s & 1) && s >= 3 && s < S_) {
      int e2 = y[((s-3) >> 1)*B_ + b];
      if (e != 0 && e != e2) am = 0.f;
    }
    amask[idx] = am;
  }
}

// ---------------- cast ctx (f32) -> A (bf16), element-wise ---------------
__global__ void cast_a_kernel(const float* __restrict__ ctx, bf16* __restrict__ A) {
  int i = blockIdx.x * blockDim.x + threadIdx.x;  // exactly 819200 threads
  float4 v = ((const float4*)ctx)[i];
  union { bf16 h[4]; uint2 u; } p;
  p.h[0] = (bf16)v.x; p.h[1] = (bf16)v.y; p.h[2] = (bf16)v.z; p.h[3] = (bf16)v.w;
  ((uint2*)A)[i] = p.u;
}

// ---------------- transpose W [256][4001] f32 -> Wt [4096][256] bf16 -----
__global__ void trans_w_kernel(const float* __restrict__ W, bf16* __restrict__ Wt) {
  __shared__ float tile[32][33];
  const int c = threadIdx.x & 31, r = threadIdx.x >> 5;  // 32x8 threads
  const int n0 = blockIdx.x * 32, k0 = blockIdx.y * 32;
  for (int rr = r; rr < 32; rr += 8) {
    int n = n0 + c;
    tile[rr][c] = (n < V_) ? W[(size_t)(k0+rr)*V_ + n] : 0.f;
  }
  __syncthreads();
  for (int rr = r; rr < 32; rr += 8) {
    Wt[(size_t)(n0+rr)*D_ + k0 + c] = (bf16)tile[c][rr];
  }
}

// ---------------- GEMM: logits = A x Wt^T + bias -> out[1..] (f32) -------
// 128x128 tile, BK=64, mfma_f32_16x16x32_bf16, wave tile 64x64 (4x4 C-tiles)
// LDS row stride 72 bf16 (144 B = 9*16 B) -> bank-uniform b128 reads.
// XCD-aware block swizzle (bijective, 3200%8==0) for L2-local panel reuse.
__global__ __launch_bounds__(256) void gemm_kernel(
    const bf16* __restrict__ A, const bf16* __restrict__ Wt,
    const float* __restrict__ bias, float* __restrict__ out) {
  __shared__ bf16 smA[128*72];
  __shared__ bf16 smB[128*72];
  const int tid = threadIdx.x;
  const int l = tid & 63, w = tid >> 6;
  const int wr = w >> 1, wc = w & 1;
  const int orig = blockIdx.y * 32 + blockIdx.x;       // 0..3199
  const int virt = (orig & 7) * 400 + (orig >> 3);     // XCD-chunked remap
  const int n0 = (virt & 31) * 128, m0 = (virt >> 5) * 128;

  f32x4 acc[4][4];
#pragma unroll
  for (int i = 0; i < 4; i++)
#pragma unroll
    for (int j = 0; j < 4; j++) acc[i][j] = (f32x4){0.f, 0.f, 0.f, 0.f};

  for (int kt = 0; kt < 4; kt++) {
#pragma unroll
    for (int r = 0; r < 4; r++) {
      int j = (w*4 + r)*64 + l;        // 0..1023 16B-chunk slot
      int row = j >> 3, c = j & 7;     // row 0..127, chunk 0..7 (8 bf16)
      bf16x8 va = *(const bf16x8*)(A  + (size_t)(m0+row)*D_ + kt*64 + c*8);
      bf16x8 vb = *(const bf16x8*)(Wt + (size_t)(n0+row)*D_ + kt*64 + c*8);
      *(bf16x8*)((char*)smA + row*144 + (c<<4)) = va;
      *(bf16x8*)((char*)smB + row*144 + (c<<4)) = vb;
    }
    __syncthreads();
#pragma unroll
    for (int ks = 0; ks < 2; ks++) {
      bf16x8 af[4], bfr[4];
      const int cidx = ks*4 + (l >> 4);
#pragma unroll
      for (int t = 0; t < 4; t++) {
        int arow = wr*64 + t*16 + (l & 15);
        af[t]  = *(const bf16x8*)((const char*)smA + arow*144 + (cidx<<4));
        int brow = wc*64 + t*16 + (l & 15);
        bfr[t] = *(const bf16x8*)((const char*)smB + brow*144 + (cidx<<4));
      }
#pragma unroll
      for (int i = 0; i < 4; i++)
#pragma unroll
        for (int j = 0; j < 4; j++)
          acc[i][j] = __builtin_amdgcn_mfma_f32_16x16x32_bf16(af[i], bfr[j], acc[i][j], 0, 0, 0);
    }
    __syncthreads();
  }
  // epilogue: C layout col=lane&15, row=(lane>>4)*4+reg (verified m89/m91)
#pragma unroll
  for (int j = 0; j < 4; j++) {
    int gn = n0 + wc*64 + j*16 + (l & 15);
    if (gn < V_) {
      float bv = bias[gn];
#pragma unroll
      for (int i = 0; i < 4; i++) {
        int rbase = m0 + wr*64 + i*16 + ((l >> 4) << 2);
#pragma unroll
        for (int rg = 0; rg < 4; rg++) {
          out[1 + (size_t)(rbase + rg)*V_ + gn] = acc[i][j][rg] + bv;
        }
      }
    }
  }
}

// ---------------- per-row log_softmax in place + emit gather -------------
// emit stored TRANSPOSED [b][t][SP], log2 domain (pre-scaled by log2(e)).
__global__ __launch_bounds__(256) void softmax_gather_kernel(
    float* __restrict__ out, const int* __restrict__ ext, float* __restrict__ emit) {
  __shared__ float srow[4096];
  __shared__ float red[8];
  const int row = blockIdx.x, tid = threadIdx.x;
  float* rp = out + 1 + (size_t)row * V_;
  float v[16];
  float mx = NEGF;
#pragma unroll
  for (int j = 0; j < 16; j++) {
    int c = tid + j*256;
    v[j] = (c < V_) ? rp[c] : NEGF;
    mx = fmaxf(mx, v[j]);
  }
#pragma unroll
  for (int o = 32; o > 0; o >>= 1) mx = fmaxf(mx, __shfl_xor(mx, o));
  if ((tid & 63) == 0) red[tid >> 6] = mx;
  __syncthreads();
  mx = fmaxf(fmaxf(red[0], red[1]), fmaxf(red[2], red[3]));
  float sm = 0.f;
#pragma unroll
  for (int j = 0; j < 16; j++) sm += __builtin_amdgcn_exp2f((v[j] - mx) * L2E);
#pragma unroll
  for (int o = 32; o > 0; o >>= 1) sm += __shfl_xor(sm, o);
  if ((tid & 63) == 0) red[4 + (tid >> 6)] = sm;
  __syncthreads();
  const float lse = mx + __builtin_amdgcn_logf(red[4] + red[5] + red[6] + red[7]) * LN2;
#pragma unroll
  for (int j = 0; j < 16; j++) {
    int c = tid + j*256;
    if (c < V_) {
      float lp = v[j] - lse;
      rp[c] = lp;        // final logps output
      srow[c] = lp;      // for the emit gather below
    }
  }
  __syncthreads();
  // emit in log2 domain: alpha runs in log2, avoids mul-by-L2E per step
  if (tid < SP) {
    float e = NEGF;
    if (tid < S_) e = srow[ext[(row & (B_-1))*SP + tid]] * L2E;
    emit[((size_t)(row & (B_-1))*T_ + (row >> 4))*SP + tid] = e;
  }
}

// ---------------- CTC alpha recursion (lazy-logsumexp pairs) -------------
// R8: R7 landed ~117us (350 cyc/step) vs predicted 45-75 -- the arithmetic
// chain (dpp->max3->add, ~22 cyc) no longer explains the time. Suspect: the
// PER-STEP sched_barrier(0) fenced every step, forbidding the scheduler
// from overlapping adjacent steps' exp2 tails (8-10 quarter-rate trans ops
// each). Fix: group-level double buffer -- 8 loads as a block into B, ONE
// sched_barrier(0) (still prevents the R1/R6 load-sinking), then 8
// fence-free steps over A; ping-pong via 2x unroll (static indexing, rule
// #20). Loads keep 8 steps (~1200 cyc) of slack >= ~900 cyc HBM latency.
// Also: 2-source (blank) states use r' = fmaf(r_lo, exp2(-|d|), r_hi) --
// one exp2 instead of two; 8 trans/step total instead of 10.
__device__ __forceinline__ float dpp_shr1f(float x, float oldv) {
  // lane l gets lane l-1's x; lane 0 keeps 'oldv' (bound_ctrl=0)
  int r = __builtin_amdgcn_update_dpp(__float_as_int(oldv), __float_as_int(x),
                                      0x138 /*wave_shr:1*/, 0xf, 0xf, false);
  return __int_as_float(r);
}
#define EX2 __builtin_amdgcn_exp2f

__global__ __launch_bounds__(64) void alpha_kernel(
    const float* __restrict__ emit, const float* __restrict__ amp,
    const int* __restrict__ lens, float* __restrict__ out) {
  __shared__ float aSm[256];
  __shared__ float aSr[256];
  const int b = blockIdx.x, l = threadIdx.x;
  const bool act = (l < 51);  // 51*4 = 204 = SP
  const float* ebase = emit + (size_t)b*T_*SP;
  const float4 NEG4 = make_float4(NEGF, NEGF, NEGF, NEGF);

  float4 am = act ? *(const float4*)(amp + b*SP + 4*l) : NEG4;
  float m0 = NEGF, m1 = NEGF, m2 = NEGF, m3 = NEGF;
  float r0 = 1.f, r1 = 1.f, r2 = 1.f, r3 = 1.f;
  if (l == 0) { m0 = ebase[0]; m1 = ebase[1]; }  // alpha0: only s=0,1

  auto ld = [&](int t) -> float4 {
    return *(const float4*)(ebase + (size_t)t*SP + 4*l);
  };

  auto step = [&](float4 cur) {
    float shm = dpp_shr1f(m3, NEGF);  // state 4l-1 (prev lane's 4l+3)
    float shr = dpp_shr1f(r3, 1.f);
    // state 4l (even/blank): sources (m0,r0),(shm,shr) -- 1 exp2
    float d0 = m0 - shm;
    float p0 = fmaxf(m0, shm);
    float e0 = EX2(-fabsf(d0));
    float n0 = fmaf((d0 >= 0.f ? shr : r0), e0, (d0 >= 0.f ? r0 : shr));
    // state 4l+1 (odd): sources (m1,r1),(m0,r0),(shm+am.y,shr) -- 3 exp2
    float sy = shm + am.y;
    float p1 = fmaxf(fmaxf(m1, m0), sy);
    float n1 = fmaf(r1, EX2(m1 - p1), fmaf(r0, EX2(m0 - p1), shr * EX2(sy - p1)));
    // state 4l+2 (even/blank): sources (m2,r2),(m1,r1) -- 1 exp2
    float d2 = m2 - m1;
    float p2 = fmaxf(m2, m1);
    float e2 = EX2(-fabsf(d2));
    float n2 = fmaf((d2 >= 0.f ? r1 : r2), e2, (d2 >= 0.f ? r2 : r1));
    // state 4l+3 (odd): sources (m3,r3),(m2,r2),(m1+am.w,r1) -- 3 exp2
    float aw = m1 + am.w;
    float p3 = fmaxf(fmaxf(m3, m2), aw);
    float n3 = fmaf(r3, EX2(m3 - p3), fmaf(r2, EX2(m2 - p3), r1 * EX2(aw - p3)));
    m0 = p0 + cur.x; m1 = p1 + cur.y; m2 = p2 + cur.z; m3 = p3 + cur.w;
    r0 = n0; r1 = n1; r2 = n2; r3 = n3;
  };

  auto fold4 = [&]() {
    // exact: r = mant in [1,2), m += exponent (r >= 1 always: each new r
    // is >= one of the previous r's, all start at 1)
    uint32_t b0 = __float_as_uint(r0), b1 = __float_as_uint(r1);
    uint32_t b2 = __float_as_uint(r2), b3 = __float_as_uint(r3);
    m0 += (float)((int)(b0 >> 23) - 127); r0 = __uint_as_float((b0 & 0x007FFFFFu) | 0x3F800000u);
    m1 += (float)((int)(b1 >> 23) - 127); r1 = __uint_as_float((b1 & 0x007FFFFFu) | 0x3F800000u);
    m2 += (float)((int)(b2 >> 23) - 127); r2 = __uint_as_float((b2 & 0x007FFFFFu) | 0x3F800000u);
    m3 += (float)((int)(b3 >> 23) - 127); r3 = __uint_as_float((b3 & 0x007FFFFFu) | 0x3F800000u);
  };

  // double-buffered 8-step groups: 100 groups cover t = 1..799 (+1 dup)
  float4 A8[8], B8[8];
#pragma unroll
  for (int j = 0; j < 8; j++) A8[j] = ld(1 + j);       // group 0: t=1..8

  for (int g = 0; g < 49; ++g) {   // groups 2g (A) and 2g+1 (B)
    const int t0 = 9 + 16*g;       // B: t = 9+16g .. 16+16g   (max 784)
#pragma unroll
    for (int j = 0; j < 8; j++) B8[j] = ld(t0 + j);
    __builtin_amdgcn_sched_barrier(0);   // pin loads above the steps
#pragma unroll
    for (int j = 0; j < 8; j++) step(A8[j]);
    fold4();
    const int t1 = 17 + 16*g;      // A: t = 17+16g .. 24+16g  (max 792)
#pragma unroll
    for (int j = 0; j < 8; j++) A8[j] = ld(t1 + j);
    __builtin_amdgcn_sched_barrier(0);
#pragma unroll
    for (int j = 0; j < 8; j++) step(B8[j]);
    fold4();
  }
  // group 98: consume A8 (t=785..792); prefetch tail t=793..799 (+dup)
#pragma unroll
  for (int j = 0; j < 8; j++) { int t = 793 + j; if (t > 799) t = 799; B8[j] = ld(t); }
  __builtin_amdgcn_sched_barrier(0);
#pragma unroll
  for (int j = 0; j < 8; j++) step(A8[j]);
  fold4();
  // group 99 (tail): t = 793..799, 7 steps
#pragma unroll
  for (int j = 0; j < 7; j++) step(B8[j]);

  aSm[4*l+0] = m0; aSm[4*l+1] = m1; aSm[4*l+2] = m2; aSm[4*l+3] = m3;
  aSr[4*l+0] = r0; aSr[4*l+1] = r1; aSr[4*l+2] = r2; aSr[4*l+3] = r3;
  __syncthreads();
  if (l == 0) {
    int e = 2 * lens[b];
    float la = aSm[e]   + __builtin_amdgcn_logf(aSr[e]);
    float lb = aSm[e-1] + __builtin_amdgcn_logf(aSr[e-1]);
    float mm = fmaxf(la, lb);
    float ll2 = mm + log2f(exp2f(la - mm) + exp2f(lb - mm));
    atomicAdd(out, -ll2 * LN2);  // loss = -sum_b ll
  }
}

// ---------------- launch ----------------
extern "C" void kernel_launch(void* const* d_in, const int* in_sizes, int n_in,
                              void* d_out, int out_size, void* d_ws, size_t ws_size,
                              hipStream_t stream) {
  const float* ctx  = (const float*)d_in[0];  // [800,16,256]
  const int*   y    = (const int*)  d_in[1];  // [100,16]
  const float* W    = (const float*)d_in[2];  // [256,4001]
  const float* bias = (const float*)d_in[3];  // [4001]
  float* out = (float*)d_out;                 // [1 + 800*16*4001]
  char* ws = (char*)d_ws;
  bf16*  A     = (bf16*) (ws + A_OFF);
  bf16*  Wt    = (bf16*) (ws + WT_OFF);
  float* emit  = (float*)(ws + EMIT_OFF);
  int*   ext   = (int*)  (ws + EXT_OFF);
  float* amp   = (float*)(ws + AMASK_OFF);
  int*   lens  = (int*)  (ws + LENS_OFF);

  hipLaunchKernelGGL(prep_kernel, dim3(1), dim3(256), 0, stream, y, out, ext, amp, lens);
  hipLaunchKernelGGL(cast_a_kernel, dim3(3200), dim3(256), 0, stream, ctx, A);
  hipLaunchKernelGGL(trans_w_kernel, dim3(128, 8), dim3(256), 0, stream, W, Wt);
  hipLaunchKernelGGL(gemm_kernel, dim3(32, 100), dim3(256), 0, stream, A, Wt, bias, out);
  hipLaunchKernelGGL(softmax_gather_kernel, dim3(12800), dim3(256), 0, stream, out, ext, emit);
  hipLaunchKernelGGL(alpha_kernel, dim3(16), dim3(64), 0, stream, emit, amp, lens, out);
}